// Round 11
// baseline (133.727 us; speedup 1.0000x reference)
//
#include <hip/hip_runtime.h>
#include <hip/hip_bf16.h>

// Motion-detection Gauss-LIF SNN:
//   K01 (fused, heterogeneous 256-thread blocks):
//     blocks [0,256):    conv(16x9x9) via MFMA bf16 16x16x32 + LIF1 ->
//                        Z1 [800][65536] i8 {0,1} in k'-order.
//                        NEW: limb-interleaved tile (uint = xm<<16|xh),
//                        4 offsets/wave via 3x ds_read_b128 + v_perm split,
//                        2 strips/block (4 output rows, shared 13-row tile).
//                        MFMA term order identical to r10 -> bit-identical z.
//     blocks [256,6656): w1 -> i8 (A,B) split, k'-permuted, conflict-free LDS.
//   K2: Z1 @ w1^T via two mfma_i32_16x16x64_i8 (exact i32). BM=128, KSPL=32,
//       XCD-chunked (r10, proven).
//   K2b: reduce partials; K3: sequential LIF2+FC2+LIF3 scan.
// LIF recurrences __fmul_rn/__fadd_rn (no contract). Deterministic order.

typedef __attribute__((ext_vector_type(8))) short short8;
typedef __attribute__((ext_vector_type(4))) float f32x4;
typedef __attribute__((ext_vector_type(4))) int   i32x4;

#define B_   16
#define T_   50
#define HW_  4096
#define K1N  65536
#define M_   800
#define N2_  200
#define NP_  256
#define KSPL 32
#define BM2  128
#define BK2  64
#define KCH  (K1N / KSPL)  // 2048
#define MT2  7             // ceil(800/128)
#define RS   84            // conv tile row stride (uints)
#define TR13 13            // 12 data rows + 1 zero pad row (dy=9 reads)
#define TILEU (TR13 * RS)  // 1092 uints per buffer
#define NCONV 256
#define NPERM (200 * 32)

static __device__ __forceinline__ short8 mk8(uint a, uint b, uint c, uint d){
  union { uint u[4]; short8 v; } x;
  x.u[0] = a; x.u[1] = b; x.u[2] = c; x.u[3] = d;
  return x.v;
}

// ---------------------------------------------------------------- conv phase
// Wave covers 4 offsets {4w..4w+3} of one strip. Per kstep: 12 uints
// (3x b128) -> 20 v_perm (lo/hi limb splits, shared across offsets) ->
// 12 MFMA. Term order per (offset, ks): hh, mh, hl  == r10 order.
static __device__ __forceinline__ void conv_phase4(const uint* __restrict__ T,
                                                   int bdw,
                                                   const short8 (&afh)[5],
                                                   const short8 (&afl)[5],
                                                   f32x4 (&acc)[4]){
  #pragma unroll
  for (int ks = 0; ks < 5; ++ks){
    const uint* p = T + bdw + 2 * RS * ks;
    uint4 a = *(const uint4*)(p);
    uint4 b = *(const uint4*)(p + 4);
    uint4 c = *(const uint4*)(p + 8);
    uint u[12] = {a.x, a.y, a.z, a.w, b.x, b.y, b.z, b.w, c.x, c.y, c.z, c.w};
    uint lo[10], hi[10];
    #pragma unroll
    for (int i = 0; i < 10; ++i){
      lo[i] = __builtin_amdgcn_perm(u[i + 1], u[i], 0x05040100);  // xh pair
      hi[i] = __builtin_amdgcn_perm(u[i + 1], u[i], 0x07060302);  // xm pair
    }
    #pragma unroll
    for (int j = 0; j < 4; ++j){
      short8 bh = mk8(lo[j], lo[j + 2], lo[j + 4], lo[j + 6]);
      short8 bm = mk8(hi[j], hi[j + 2], hi[j + 4], hi[j + 6]);
      acc[j] = __builtin_amdgcn_mfma_f32_16x16x32_bf16(afh[ks], bh, acc[j], 0, 0, 0);
      acc[j] = __builtin_amdgcn_mfma_f32_16x16x32_bf16(afh[ks], bm, acc[j], 0, 0, 0);
      acc[j] = __builtin_amdgcn_mfma_f32_16x16x32_bf16(afl[ks], bh, acc[j], 0, 0, 0);
    }
  }
}

static __device__ __forceinline__ uint pack_px(float v){
  __hip_bfloat16 h = __float2bfloat16(v);
  float t1 = v - __bfloat162float(h);
  __hip_bfloat16 m = __float2bfloat16(t1);
  uint uh = *reinterpret_cast<ushort*>(&h);
  uint um = *reinterpret_cast<ushort*>(&m);
  return (um << 16) | uh;
}

// ---------------------------------------------------------------- K01
// conv smem: Ah[2560]us | Alo[2560]us | 2 x TILEU uints  = 18976 B
// perm smem: la[528] | lb[528] uints (o-padded, conflict-free)
__global__ __launch_bounds__(256) void k01_fused(const float* __restrict__ x,
                                                 const float* __restrict__ kern,
                                                 const float* __restrict__ w1,
                                                 unsigned char* __restrict__ zout,
                                                 char* __restrict__ wa,
                                                 char* __restrict__ wb){
  __shared__ __align__(16) uint smem[4744];   // 18976 B
  const int bid = blockIdx.x;
  const int tid = threadIdx.x;

  if (bid >= NCONV){
    // ---------------- w1 -> i8 (A,B) split + k'-permute, conflict-free ------
    uint* la = smem;
    uint* lb = smem + 528;
    const int bid2 = bid - NCONV;
    const int n = bid2 >> 5;
    const int strip = bid2 & 31;
    const int p128 = tid & 127;
    const int qp   = tid >> 7;
    const int o = p128 & 7, s = p128 >> 3;
    const float* src = w1 + (size_t)n * K1N + strip * 128 + p128;
    #pragma unroll
    for (int qi = 0; qi < 2; ++qi){
      const int q = 2 * qp + qi;
      uint ua = 0, ub = 0;
      #pragma unroll
      for (int r = 0; r < 4; ++r){
        float v = src[(size_t)(4 * q + r) * 4096];
        float af = rintf(v * 16384.f);
        float rr = v - af * 0x1p-14f;
        float bf = rintf(rr * 0x1p22f);
        int A = (int)af, Bq = (int)bf;
        if (Bq == 128){ A += 1; Bq = -128; }
        ua |= ((uint)(A & 255))  << (8 * r);
        ub |= ((uint)(Bq & 255)) << (8 * r);
      }
      const int u = 64 * o + 4 * s + q + o;
      la[u] = ua;
      lb[u] = ub;
    }
    __syncthreads();
    {
      const int j0 = 2 * tid;
      const int o2 = j0 >> 6;
      uint a0 = la[j0 + o2], a1 = la[j0 + 1 + o2];
      uint b0 = lb[j0 + o2], b1 = lb[j0 + 1 + o2];
      const size_t ob = (size_t)n * K1N + strip * 2048 + (size_t)j0 * 4;
      *(uint2*)(wa + ob) = make_uint2(a0, a1);
      *(uint2*)(wb + ob) = make_uint2(b0, b1);
    }
    return;
  }

  // ---------------- conv + LIF1, 2 strips/block, 4 offsets/wave ------------
  ushort* Ah  = (ushort*)smem;                 // 2560 ushorts
  ushort* Alo = (ushort*)smem + 2560;
  uint*   Tt  = smem + 2560;                   // 2 x TILEU uints

  const int u16 = bid & 15;                    // row-quad index (4 rows)
  const int b   = bid >> 4;
  const int wv = tid >> 6;
  const int h  = wv >> 1;                      // strip-half within block
  const int w  = wv & 1;                       // offset group {4w..4w+3}
  const int l  = tid & 63;
  const int q  = l >> 4;
  const int s  = l & 15;

  // taps: kh + kl bf16 split, zero-padded to 10x16
  for (int slot = tid; slot < 16 * 160; slot += 256){
    int ch = slot / 160, kk = slot - ch * 160;
    int dy = kk >> 4, dx = kk & 15;
    float v = 0.f;
    if (dy < 9 && dx < 9) v = kern[ch * 81 + dy * 9 + dx];
    __hip_bfloat16 hh = __float2bfloat16(v);
    float hf = __bfloat162float(hh);
    __hip_bfloat16 lo = __float2bfloat16(v - hf);
    Ah[slot]  = *reinterpret_cast<ushort*>(&hh);
    Alo[slot] = *reinterpret_cast<ushort*>(&lo);
  }
  // zero pad row 12 of both buffers (read by dy=9 lanes, taps are zero)
  for (int j = tid; j < 2 * RS; j += 256){
    int bf = j / RS, cc = j - bf * RS;
    Tt[bf * TILEU + 12 * RS + cc] = 0u;
  }

  // staging geometry (threads 0..239): r = row 0..11, c4 = 4-px group 0..19
  const bool sact = tid < 240;
  const int sr = tid / 20, sc4 = tid - sr * 20;
  const int imr = 4 * u16 - 4 + sr;
  const bool sin = sact && imr >= 0 && imr < 64 && sc4 >= 1 && sc4 <= 16;
  const float* xb = x + (size_t)b * (T_ * HW_);
  const float* xsrc = xb + (sin ? (imr * 64 + (sc4 - 1) * 4) : 0);
  const int eb = sr * RS + sc4 * 4;

  // stage t=0 tile into buf0
  {
    float4 f0 = make_float4(0.f, 0.f, 0.f, 0.f);
    if (sin) f0 = *(const float4*)(xsrc);
    if (sact){
      uint4 pk = make_uint4(pack_px(f0.x), pack_px(f0.y), pack_px(f0.z), pack_px(f0.w));
      *(uint4*)(Tt + eb) = pk;
    }
  }
  __syncthreads();

  // preload A-fragments
  short8 afh[5], afl[5];
  #pragma unroll
  for (int ks = 0; ks < 5; ++ks){
    afh[ks] = *(const short8*)(Ah + s * 160 + ks * 32 + q * 8);
    afl[ks] = *(const short8*)(Alo + s * 160 + ks * 32 + q * 8);
  }

  // window base (uints): row = 2h + p0, col X0 = 8(s&7)+8(q&1)+4w  (4-aligned)
  const int p0  = (s >> 3) + (q >> 1);
  const int bdw = (2 * h + p0) * RS + 8 * (s & 7) + 8 * (q & 1) + 4 * w;
  const int S   = 2 * u16 + h;                 // strip index 0..31

  float m1v[4][4];
  #pragma unroll
  for (int j = 0; j < 4; ++j)
    #pragma unroll
    for (int r = 0; r < 4; ++r) m1v[j][r] = 0.f;

  for (int t = 0; t < T_; ++t){
    __syncthreads();                           // tile t&1 ready
    float4 nfx = make_float4(0.f, 0.f, 0.f, 0.f);
    if (t + 1 < T_ && sin) nfx = *(const float4*)(xsrc + (size_t)(t + 1) * HW_);

    const int bb = t & 1;
    f32x4 acc[4];
    #pragma unroll
    for (int j = 0; j < 4; ++j) acc[j] = (f32x4)(0.f);
    conv_phase4(Tt + bb * TILEU, bdw, afh, afl, acc);

    // LIF1 + i8 spike store (4 offsets)
    const size_t zr = ((size_t)(t * B_ + b)) * K1N + (size_t)S * 2048 + s * 16 + q * 4;
    #pragma unroll
    for (int j = 0; j < 4; ++j){
      uint zw = 0;
      #pragma unroll
      for (int r = 0; r < 4; ++r){
        float m = m1v[j][r];
        float nm = (m > 1.0f) ? 0.0f : __fadd_rn(__fmul_rn(0.9f, m), acc[j][r]);
        m1v[j][r] = nm;
        if (nm > 1.0f) zw |= (1u << (8 * r));
      }
      *(uint*)(zout + zr + (size_t)(4 * w + j) * 256) = zw;
    }

    // stage next tile into the other buffer
    if (t + 1 < T_ && sact){
      uint4 pk = make_uint4(pack_px(nfx.x), pack_px(nfx.y), pack_px(nfx.z), pack_px(nfx.w));
      *(uint4*)(Tt + (bb ^ 1) * TILEU + eb) = pk;
    }
  }
}

// ---------------------------------------------------------------- K2 prefetch loader (i8)
static __device__ __forceinline__ void k2_load(const unsigned char* __restrict__ z,
                                               const char* __restrict__ wa,
                                               const char* __restrict__ wb,
                                               int m0, int kg, int tid,
                                               uint4& pa, uint4 pb[4]){
  {
    int row = tid >> 2, c16 = tid & 3;
    int m = m0 + row;
    pa = make_uint4(0, 0, 0, 0);
    if (m < M_) pa = *(const uint4*)(z + (size_t)m * K1N + kg + c16 * 16);
  }
  #pragma unroll
  for (int i = 0; i < 4; ++i){
    int idx = tid + 512 * i;
    int g   = idx >> 2;
    int c16 = idx & 3;
    int sel = g >> 8;
    int r   = g & 255;
    const char* src = sel ? wb : wa;
    pb[i] = make_uint4(0, 0, 0, 0);
    if (r < N2_) pb[i] = *(const uint4*)(src + (size_t)r * K1N + kg + c16 * 16);
  }
}

// ---------------------------------------------------------------- K2: i8 MFMA GEMM (r10)
__global__ __launch_bounds__(512) void k2_gemm(const unsigned char* __restrict__ z,
                                               const char* __restrict__ wa,
                                               const char* __restrict__ wb,
                                               float* __restrict__ P){
  __shared__ __align__(16) unsigned char Al[128 * 80];
  __shared__ __align__(16) unsigned char Bw[512 * 80];

  const int bid = blockIdx.x;
  const int L = (bid & 7) * 28 + (bid >> 3);
  const int ks = L / MT2;
  const int mt = L % MT2;
  const int m0 = mt * BM2;
  const int k0 = ks * KCH;
  const int tid = threadIdx.x;
  const int wv = tid >> 6;
  const int mh = wv >> 2;
  const int nq = wv & 3;
  const int l  = tid & 63;
  const int lr = l & 15;
  const int lq = l >> 4;

  const i32x4 zero4 = {0, 0, 0, 0};
  i32x4 accA[4][4], accB[4][4];
  #pragma unroll
  for (int mf = 0; mf < 4; ++mf)
    #pragma unroll
    for (int nf = 0; nf < 4; ++nf){ accA[mf][nf] = zero4; accB[mf][nf] = zero4; }

  uint4 pa, pb[4];
  k2_load(z, wa, wb, m0, k0, tid, pa, pb);

  #pragma unroll 1
  for (int kc = 0; kc < KCH; kc += BK2){
    {
      int row = tid >> 2, c16 = tid & 3;
      *(uint4*)(Al + row * 80 + c16 * 16) = pa;
    }
    #pragma unroll
    for (int i = 0; i < 4; ++i){
      int idx = tid + 512 * i;
      int g   = idx >> 2;
      int c16 = idx & 3;
      *(uint4*)(Bw + g * 80 + c16 * 16) = pb[i];
    }
    __syncthreads();

    if (kc + BK2 < KCH) k2_load(z, wa, wb, m0, k0 + kc + BK2, tid, pa, pb);

    i32x4 af[4], ba[4], bbf[4];
    #pragma unroll
    for (int mf = 0; mf < 4; ++mf)
      af[mf] = *(const i32x4*)(Al + (mh * 64 + mf * 16 + lr) * 80 + lq * 16);
    #pragma unroll
    for (int nf = 0; nf < 4; ++nf){
      ba[nf]  = *(const i32x4*)(Bw + (nq * 64 + nf * 16 + lr) * 80 + lq * 16);
      bbf[nf] = *(const i32x4*)(Bw + (256 + nq * 64 + nf * 16 + lr) * 80 + lq * 16);
    }
    #pragma unroll
    for (int mf = 0; mf < 4; ++mf)
      #pragma unroll
      for (int nf = 0; nf < 4; ++nf){
        accA[mf][nf] = __builtin_amdgcn_mfma_i32_16x16x64_i8(af[mf], ba[nf],  accA[mf][nf], 0, 0, 0);
        accB[mf][nf] = __builtin_amdgcn_mfma_i32_16x16x64_i8(af[mf], bbf[nf], accB[mf][nf], 0, 0, 0);
      }
    __syncthreads();
  }

  #pragma unroll
  for (int mf = 0; mf < 4; ++mf)
    #pragma unroll
    for (int nf = 0; nf < 4; ++nf)
      #pragma unroll
      for (int r = 0; r < 4; ++r){
        int m = m0 + mh * 64 + mf * 16 + lq * 4 + r;
        int n = nq * 64 + nf * 16 + lr;
        if (m < M_ && n < N2_)
          P[((size_t)ks * M_ + m) * N2_ + n] =
            fmaf((float)accA[mf][nf][r], 0x1p-14f, (float)accB[mf][nf][r] * 0x1p-22f);
      }
}

// ---------------------------------------------------------------- K2b: reduce k-splits
__global__ __launch_bounds__(256) void k2b_reduce(const float* __restrict__ P,
                                                  float* __restrict__ G2){
  int j = blockIdx.x * 256 + threadIdx.x;
  if (j >= M_ * N2_) return;
  float s = 0.f;
  #pragma unroll
  for (int ks = 0; ks < KSPL; ++ks) s += P[(size_t)ks * (M_ * N2_) + j];
  G2[j] = s;
}

// ---------------------------------------------------------------- K3: LIF2+FC2+LIF3 scan
__global__ __launch_bounds__(256) void k3_scan(const float* __restrict__ G2,
                                               const float* __restrict__ w2,
                                               float* __restrict__ out){
  const int b = blockIdx.x;
  const int tid = threadIdx.x;
  const float w = (tid < N2_) ? w2[tid] : 0.f;
  float m2 = 0.f, m3 = 0.f;
  __shared__ float part[4];

  float nxt = (tid < N2_) ? G2[(size_t)b * N2_ + tid] : 0.f;
  for (int t = 0; t < T_; ++t){
    float g2v = nxt;
    if (t < T_ - 1 && tid < N2_) nxt = G2[(size_t)((t + 1) * B_ + b) * N2_ + tid];
    float nm = (m2 > 1.0f) ? 0.f : __fadd_rn(__fmul_rn(0.9f, m2), g2v);
    m2 = nm;
    float s = (m2 > 1.0f) ? w : 0.f;
    #pragma unroll
    for (int off = 32; off > 0; off >>= 1) s += __shfl_down(s, off, 64);
    if ((tid & 63) == 0) part[tid >> 6] = s;
    __syncthreads();
    if (tid == 0){
      float g3 = (part[0] + part[1]) + (part[2] + part[3]);
      m3 = __fadd_rn(__fmul_rn(0.95f, m3), g3);
      out[b * T_ + t] = m3;
    }
    __syncthreads();
  }
}

// ---------------------------------------------------------------- host
extern "C" void kernel_launch(void* const* d_in, const int* in_sizes, int n_in,
                              void* d_out, int out_size, void* d_ws, size_t ws_size,
                              hipStream_t stream){
  const float* x    = (const float*)d_in[0];
  const float* kern = (const float*)d_in[1];
  const float* w1   = (const float*)d_in[2];
  const float* w2   = (const float*)d_in[3];
  float* out = (float*)d_out;

  char* p = (char*)d_ws;
  unsigned char* z8 = (unsigned char*)p;     p += (size_t)M_ * K1N;
  char* wa = p;                              p += (size_t)NP_ * K1N;
  char* wb = p;                              p += (size_t)NP_ * K1N;
  float* P  = (float*)p;                     p += (size_t)KSPL * M_ * N2_ * 4;
  float* G2 = (float*)p;                     p += (size_t)M_ * N2_ * 4;

  size_t need = (size_t)(p - (char*)d_ws);
  if (ws_size < need) return;

  hipLaunchKernelGGL(k01_fused,  dim3(NCONV + NPERM), dim3(256), 0, stream,
                     x, kern, w1, z8, wa, wb);
  hipLaunchKernelGGL(k2_gemm,    dim3(MT2 * KSPL), dim3(512), 0, stream, z8, wa, wb, P);
  hipLaunchKernelGGL(k2b_reduce, dim3((M_ * N2_ + 255) / 256), dim3(256), 0, stream, P, G2);
  hipLaunchKernelGGL(k3_scan,    dim3(B_), dim3(256), 0, stream, G2, w2, out);
}